// Round 1
// baseline (525.165 us; speedup 1.0000x reference)
//
#include <hip/hip_runtime.h>

// RGCN layer, MI355X. Strategy:
//  - W_r = comp @ basis precomputed once per call -> bf16, stored TRANSPOSED
//    (Wt[r][o][i]) so MFMA B-frags are 16B-contiguous ds_read_b128.
//  - Edges counting-sorted by relation (hist -> scan+tile-desc -> scatter).
//  - Main kernel: 128-edge x 128-out tile per block, gathers bf16 node rows,
//    scales by norm, 16x16x32 bf16 MFMA (2x2 waves, 4x4 frags each),
//    atomicAdd fp32 rows into d_out.
//  - Residual relu(x@W_res+b) via same GEMM structure -> ws.
//  - Fused bias+relu+residual+BN-stats kernel, then BN apply kernel.
// LDS: A,B tiles 128x128 bf16 = 64KB exactly, XOR chunk swizzle (no pad)
// -> 2 blocks/CU.

#define N_NODES 20000
#define E_EDGES 640000
#define R_REL   65
#define F_DIM   128
#define TM      128          // edges per tile
#define MAX_TILES 5072       // E/TM + R rounded up

typedef __attribute__((ext_vector_type(8))) short bf16x8;
typedef __attribute__((ext_vector_type(4))) float f32x4;

__device__ __forceinline__ unsigned short f2bf(float x) {
    union { float f; unsigned int u; } c; c.f = x;
    unsigned int b = c.u + 0x7fffu + ((c.u >> 16) & 1u);   // RTNE
    return (unsigned short)(b >> 16);
}
__device__ __forceinline__ float bf2f(unsigned short h) {
    union { unsigned int u; float f; } c; c.u = ((unsigned int)h) << 16;
    return c.f;
}

// ---------------- K0a: W32[r, i*128+o] = sum_b comp[r,b]*basis[b,i,o] ------
__global__ void k_basis_gemm(const float* __restrict__ comp,
                             const float* __restrict__ basis,
                             float* __restrict__ W32) {
    __shared__ float lc[16 * 65];
    int r0 = blockIdx.y * 16;
    int col = blockIdx.x * 256 + threadIdx.x;      // col = i*128+o
    for (int j = threadIdx.x; j < 16 * 65; j += 256) {
        int rr = r0 + j / 65;
        lc[j] = (rr < R_REL) ? comp[rr * 65 + (j % 65)] : 0.f;
    }
    __syncthreads();
    float acc[16];
#pragma unroll
    for (int j = 0; j < 16; ++j) acc[j] = 0.f;
    for (int k = 0; k < 65; ++k) {
        float v = basis[k * 16384 + col];
#pragma unroll
        for (int j = 0; j < 16; ++j) acc[j] += lc[j * 65 + k] * v;
    }
#pragma unroll
    for (int j = 0; j < 16; ++j) {
        int rr = r0 + j;
        if (rr < R_REL) W32[rr * 16384 + col] = acc[j];
    }
}

// ---------------- K0b: transpose fp32 [i][o] -> bf16 [o][i], per 128x128 mat
__global__ void k_transpose_bf16(const float* __restrict__ src,
                                 unsigned short* __restrict__ dst) {
    __shared__ float tile[64][65];
    int b = blockIdx.x;
    int mat = b >> 2, ot = (b >> 1) & 1, itl = b & 1;
    const float* s = src + (size_t)mat * 16384;
    unsigned short* d = dst + (size_t)mat * 16384;
    int tx = threadIdx.x & 63, ty = threadIdx.x >> 6;
    for (int it = 0; it < 16; ++it) {
        int i = ty + it * 4;
        tile[i][tx] = s[(itl * 64 + i) * 128 + ot * 64 + tx];
    }
    __syncthreads();
    for (int it = 0; it < 16; ++it) {
        int o = ty + it * 4;
        d[(ot * 64 + o) * 128 + itl * 64 + tx] = f2bf(tile[tx][o]);
    }
}

// ---------------- K0c: node feats fp32 -> bf16 ------------------------------
__global__ void k_f32_to_bf16(const float* __restrict__ x,
                              unsigned short* __restrict__ y, int n4) {
    int i = blockIdx.x * 256 + threadIdx.x;
    if (i >= n4) return;
    float4 v = reinterpret_cast<const float4*>(x)[i];
    ushort4 o;
    o.x = f2bf(v.x); o.y = f2bf(v.y); o.z = f2bf(v.z); o.w = f2bf(v.w);
    reinterpret_cast<ushort4*>(y)[i] = o;
}

// ---------------- K1a: relation histogram ----------------------------------
__global__ void k_hist(const int* __restrict__ et, int* __restrict__ ghist) {
    __shared__ int lh[R_REL];
    if (threadIdx.x < R_REL) lh[threadIdx.x] = 0;
    __syncthreads();
    for (int i = blockIdx.x * 256 + threadIdx.x; i < E_EDGES; i += gridDim.x * 256)
        atomicAdd(&lh[et[i]], 1);
    __syncthreads();
    if (threadIdx.x < R_REL) atomicAdd(&ghist[threadIdx.x], lh[threadIdx.x]);
}

// ---------------- K1b: scan + tile descriptors -----------------------------
__global__ void k_scan_tiles(const int* __restrict__ ghist, int* __restrict__ cnt,
                             int* __restrict__ ntiles_p, int* __restrict__ tile_rel,
                             int* __restrict__ tile_start, int* __restrict__ tile_len) {
    __shared__ int base[R_REL + 1], tbase[R_REL + 1];
    if (threadIdx.x == 0) {
        int b = 0, tb = 0;
        for (int r = 0; r < R_REL; ++r) {
            base[r] = b; tbase[r] = tb;
            int h = ghist[r];
            b += h; tb += (h + TM - 1) / TM;
            cnt[r] = base[r];                  // running counter for scatter
        }
        base[R_REL] = b; tbase[R_REL] = tb;
        *ntiles_p = tb;
    }
    __syncthreads();
    int nt = tbase[R_REL];
    for (int j = threadIdx.x; j < nt; j += 256) {
        int r = 0;
        while (j >= tbase[r + 1]) ++r;         // skips empty relations
        int tloc = j - tbase[r];
        int s = base[r] + tloc * TM;
        tile_rel[j] = r;
        tile_start[j] = s;
        tile_len[j] = min(TM, base[r + 1] - s);
    }
}

// ---------------- K1c: scatter edge ids into relation buckets --------------
#define SCAT_CH 2560
__global__ void k_scatter(const int* __restrict__ et, int* __restrict__ cnt,
                          int* __restrict__ perm) {
    __shared__ int lh[R_REL], lbase[R_REL];
    int c0 = blockIdx.x * SCAT_CH;
    int cend = min(c0 + SCAT_CH, E_EDGES);
    if (threadIdx.x < R_REL) lh[threadIdx.x] = 0;
    __syncthreads();
    for (int i = c0 + threadIdx.x; i < cend; i += 256) atomicAdd(&lh[et[i]], 1);
    __syncthreads();
    if (threadIdx.x < R_REL && lh[threadIdx.x] > 0)
        lbase[threadIdx.x] = atomicAdd(&cnt[threadIdx.x], lh[threadIdx.x]);
    __syncthreads();
    if (threadIdx.x < R_REL) lh[threadIdx.x] = 0;
    __syncthreads();
    for (int i = c0 + threadIdx.x; i < cend; i += 256) {
        int r = et[i];
        int p = lbase[r] + atomicAdd(&lh[r], 1);
        perm[p] = i;
    }
}

// ---------------- K2: per-relation edge GEMM + atomic scatter --------------
// LDS XOR swizzle: 16B chunk c of row p stored at chunk (c ^ (p & 15)).
__global__ __launch_bounds__(256, 2) void k_conv_gemm(
    const int* __restrict__ tile_rel, const int* __restrict__ tile_start,
    const int* __restrict__ tile_len, const int* __restrict__ ntiles_p,
    const int* __restrict__ perm, const int* __restrict__ srcA,
    const int* __restrict__ dstA, const float* __restrict__ norm,
    const unsigned short* __restrict__ node_bf,
    const unsigned short* __restrict__ Wt, float* __restrict__ hacc) {
    __shared__ unsigned short Alds[128 * 128];
    __shared__ unsigned short Blds[128 * 128];
    int tid = blockIdx.x;
    if (tid >= *ntiles_p) return;
    int r = tile_rel[tid], start = tile_start[tid], len = tile_len[tid];
    int t = threadIdx.x;
    const unsigned short* Wr = Wt + (size_t)r * 16384;
#pragma unroll
    for (int it = 0; it < 8; ++it) {               // stage W (Wt[o][i] row-major)
        int j = t + 256 * it;
        int o = j >> 4, c = j & 15;
        int cs = c ^ (o & 15);
        *reinterpret_cast<uint4*>(&Blds[o * 128 + cs * 8]) =
            *reinterpret_cast<const uint4*>(Wr + o * 128 + c * 8);
    }
#pragma unroll
    for (int it = 0; it < 8; ++it) {               // stage A (norm-scaled messages)
        int j = t + 256 * it;
        int p = j >> 4, c = j & 15;
        int cs = c ^ (p & 15);
        uint4 v = {0u, 0u, 0u, 0u};
        if (p < len) {
            int e = perm[start + p];
            float nrm = norm[e];
            int s = srcA[e];
            uint4 x = *reinterpret_cast<const uint4*>(node_bf + (size_t)s * 128 + c * 8);
            const unsigned short* xs = reinterpret_cast<const unsigned short*>(&x);
            unsigned short tmp[8];
#pragma unroll
            for (int q = 0; q < 8; ++q) tmp[q] = f2bf(bf2f(xs[q]) * nrm);
            v = *reinterpret_cast<uint4*>(tmp);
        }
        *reinterpret_cast<uint4*>(&Alds[p * 128 + cs * 8]) = v;
    }
    __syncthreads();

    int w = t >> 6, lane = t & 63;
    int wr = (w >> 1) * 64, wc = (w & 1) * 64;
    int lrow = lane & 15, quad = lane >> 4;
    f32x4 acc[4][4];
#pragma unroll
    for (int i = 0; i < 4; ++i)
#pragma unroll
        for (int j = 0; j < 4; ++j) acc[i][j] = (f32x4){0.f, 0.f, 0.f, 0.f};

#pragma unroll
    for (int ks = 0; ks < 4; ++ks) {
        int cbase = ks * 4 + quad;                 // 16B chunk index along K
        bf16x8 af[4], bf[4];
#pragma unroll
        for (int i = 0; i < 4; ++i) {
            int row = wr + i * 16 + lrow;
            int cs = cbase ^ (row & 15);
            af[i] = *reinterpret_cast<const bf16x8*>(&Alds[row * 128 + cs * 8]);
        }
#pragma unroll
        for (int j = 0; j < 4; ++j) {
            int row = wc + j * 16 + lrow;          // row in Wt == output col n
            int cs = cbase ^ (row & 15);
            bf[j] = *reinterpret_cast<const bf16x8*>(&Blds[row * 128 + cs * 8]);
        }
#pragma unroll
        for (int i = 0; i < 4; ++i)
#pragma unroll
            for (int j = 0; j < 4; ++j)
                acc[i][j] = __builtin_amdgcn_mfma_f32_16x16x32_bf16(af[i], bf[j], acc[i][j], 0, 0, 0);
    }

    // epilogue: C layout col=lane&15, row=quad*4+reg  -> atomic add into h
#pragma unroll
    for (int i = 0; i < 4; ++i) {
        int m0 = wr + i * 16 + quad * 4;
#pragma unroll
        for (int reg = 0; reg < 4; ++reg) {
            int m = m0 + reg;
            if (m < len) {
                int d = dstA[perm[start + m]];
#pragma unroll
                for (int j = 0; j < 4; ++j) {
                    int n = wc + j * 16 + lrow;
                    atomicAdd(&hacc[(size_t)d * 128 + n], acc[i][j][reg]);
                }
            }
        }
    }
}

// ---------------- K3: residual GEMM relu(x @ W_res + b_res) ----------------
__global__ __launch_bounds__(256, 2) void k_resid_gemm(
    const unsigned short* __restrict__ node_bf,
    const unsigned short* __restrict__ Wrest, const float* __restrict__ b_res,
    float* __restrict__ resid) {
    __shared__ unsigned short Alds[128 * 128];
    __shared__ unsigned short Blds[128 * 128];
    int row0 = blockIdx.x * 128;
    int t = threadIdx.x;
#pragma unroll
    for (int it = 0; it < 8; ++it) {
        int j = t + 256 * it;
        int o = j >> 4, c = j & 15;
        int cs = c ^ (o & 15);
        *reinterpret_cast<uint4*>(&Blds[o * 128 + cs * 8]) =
            *reinterpret_cast<const uint4*>(Wrest + o * 128 + c * 8);
    }
#pragma unroll
    for (int it = 0; it < 8; ++it) {
        int j = t + 256 * it;
        int p = j >> 4, c = j & 15;
        int cs = c ^ (p & 15);
        uint4 v = {0u, 0u, 0u, 0u};
        int row = row0 + p;
        if (row < N_NODES)
            v = *reinterpret_cast<const uint4*>(node_bf + (size_t)row * 128 + c * 8);
        *reinterpret_cast<uint4*>(&Alds[p * 128 + cs * 8]) = v;
    }
    __syncthreads();

    int w = t >> 6, lane = t & 63;
    int wr = (w >> 1) * 64, wc = (w & 1) * 64;
    int lrow = lane & 15, quad = lane >> 4;
    f32x4 acc[4][4];
#pragma unroll
    for (int i = 0; i < 4; ++i)
#pragma unroll
        for (int j = 0; j < 4; ++j) acc[i][j] = (f32x4){0.f, 0.f, 0.f, 0.f};
#pragma unroll
    for (int ks = 0; ks < 4; ++ks) {
        int cbase = ks * 4 + quad;
        bf16x8 af[4], bf[4];
#pragma unroll
        for (int i = 0; i < 4; ++i) {
            int row = wr + i * 16 + lrow;
            int cs = cbase ^ (row & 15);
            af[i] = *reinterpret_cast<const bf16x8*>(&Alds[row * 128 + cs * 8]);
        }
#pragma unroll
        for (int j = 0; j < 4; ++j) {
            int row = wc + j * 16 + lrow;
            int cs = cbase ^ (row & 15);
            bf[j] = *reinterpret_cast<const bf16x8*>(&Blds[row * 128 + cs * 8]);
        }
#pragma unroll
        for (int i = 0; i < 4; ++i)
#pragma unroll
            for (int j = 0; j < 4; ++j)
                acc[i][j] = __builtin_amdgcn_mfma_f32_16x16x32_bf16(af[i], bf[j], acc[i][j], 0, 0, 0);
    }
#pragma unroll
    for (int i = 0; i < 4; ++i) {
        int m0 = wr + i * 16 + quad * 4;
#pragma unroll
        for (int reg = 0; reg < 4; ++reg) {
            int grow = row0 + m0 + reg;
            if (grow < N_NODES) {
#pragma unroll
                for (int j = 0; j < 4; ++j) {
                    int n = wc + j * 16 + lrow;
                    float v = acc[i][j][reg] + b_res[n];
                    resid[(size_t)grow * 128 + n] = fmaxf(v, 0.f);
                }
            }
        }
    }
}

// ---------------- K4: h = relu(conv+bias)+resid, col sums ------------------
__global__ void k_combine_stats(float* __restrict__ h, const float* __restrict__ resid,
                                const float* __restrict__ h_bias,
                                float* __restrict__ colsum, float* __restrict__ colsumsq) {
    int col = threadIdx.x & 127, half = threadIdx.x >> 7;
    int row0 = blockIdx.x * 64;
    float bias = h_bias[col];
    float s1 = 0.f, s2 = 0.f;
    for (int it = 0; it < 32; ++it) {
        int row = row0 + half * 32 + it;
        if (row < N_NODES) {
            size_t idx = (size_t)row * 128 + col;
            float v = fmaxf(h[idx] + bias, 0.f) + resid[idx];
            h[idx] = v;
            s1 += v; s2 += v * v;
        }
    }
    __shared__ float ls1[256], ls2[256];
    ls1[threadIdx.x] = s1; ls2[threadIdx.x] = s2;
    __syncthreads();
    if (threadIdx.x < 128) {
        atomicAdd(&colsum[threadIdx.x], ls1[threadIdx.x] + ls1[threadIdx.x + 128]);
        atomicAdd(&colsumsq[threadIdx.x], ls2[threadIdx.x] + ls2[threadIdx.x + 128]);
    }
}

// ---------------- K5: BN apply ---------------------------------------------
__global__ void k_bn(float* __restrict__ h, const float* __restrict__ colsum,
                     const float* __restrict__ colsumsq, const float* __restrict__ gamma,
                     const float* __restrict__ beta) {
    __shared__ float sc[128], sh[128];
    if (threadIdx.x < 128) {
        float m = colsum[threadIdx.x] * (1.f / N_NODES);
        float var = colsumsq[threadIdx.x] * (1.f / N_NODES) - m * m;
        float s = gamma[threadIdx.x] * rsqrtf(var + 1e-5f);
        sc[threadIdx.x] = s;
        sh[threadIdx.x] = beta[threadIdx.x] - m * s;
    }
    __syncthreads();
    const int total4 = N_NODES * 32;
    for (int i = blockIdx.x * 256 + threadIdx.x; i < total4; i += gridDim.x * 256) {
        float4 v = reinterpret_cast<float4*>(h)[i];
        int c = (i * 4) & 127;
        v.x = v.x * sc[c] + sh[c];
        v.y = v.y * sc[c + 1] + sh[c + 1];
        v.z = v.z * sc[c + 2] + sh[c + 2];
        v.w = v.w * sc[c + 3] + sh[c + 3];
        reinterpret_cast<float4*>(h)[i] = v;
    }
}

extern "C" void kernel_launch(void* const* d_in, const int* in_sizes, int n_in,
                              void* d_out, int out_size, void* d_ws, size_t ws_size,
                              hipStream_t stream) {
    (void)in_sizes; (void)n_in; (void)out_size; (void)ws_size;
    const float* node_feats = (const float*)d_in[0];
    const int* src    = (const int*)d_in[1];
    const int* dst    = (const int*)d_in[2];
    const int* etype  = (const int*)d_in[3];
    const float* norm = (const float*)d_in[4];
    const float* basis = (const float*)d_in[5];
    const float* comp  = (const float*)d_in[6];
    const float* h_bias = (const float*)d_in[7];
    const float* W_res  = (const float*)d_in[8];
    const float* b_res  = (const float*)d_in[9];
    const float* gamma  = (const float*)d_in[10];
    const float* beta   = (const float*)d_in[11];

    char* ws = (char*)d_ws;
    int* ghist      = (int*)(ws + 0);
    int* cnt        = (int*)(ws + 1024);
    int* ntiles_p   = (int*)(ws + 2048);
    float* colsum   = (float*)(ws + 2560);
    float* colsumsq = (float*)(ws + 3072);
    int* tile_rel   = (int*)(ws + 4096);
    int* tile_start = (int*)(ws + 24576);
    int* tile_len   = (int*)(ws + 45056);
    float* W32      = (float*)(ws + 65536);
    unsigned short* Wt      = (unsigned short*)(ws + 4325376);
    unsigned short* Wrest   = (unsigned short*)(ws + 6455296);
    unsigned short* node_bf = (unsigned short*)(ws + 6488064);
    int* perm       = (int*)(ws + 11608064);
    float* resid    = (float*)(ws + 14168064);
    float* hacc     = (float*)d_out;

    hipMemsetAsync(ws, 0, 4096, stream);
    hipMemsetAsync(d_out, 0, (size_t)N_NODES * 128 * 4, stream);

    k_basis_gemm<<<dim3(64, 5), 256, 0, stream>>>(comp, basis, W32);
    k_transpose_bf16<<<R_REL * 4, 256, 0, stream>>>(W32, Wt);
    k_transpose_bf16<<<4, 256, 0, stream>>>(W_res, Wrest);
    k_f32_to_bf16<<<2500, 256, 0, stream>>>(node_feats, node_bf, N_NODES * 32);
    k_hist<<<256, 256, 0, stream>>>(etype, ghist);
    k_scan_tiles<<<1, 256, 0, stream>>>(ghist, cnt, ntiles_p, tile_rel, tile_start, tile_len);
    k_scatter<<<(E_EDGES + SCAT_CH - 1) / SCAT_CH, 256, 0, stream>>>(etype, cnt, perm);
    k_conv_gemm<<<MAX_TILES, 256, 0, stream>>>(tile_rel, tile_start, tile_len, ntiles_p,
                                               perm, src, dst, norm, node_bf, Wt, hacc);
    k_resid_gemm<<<(N_NODES + 127) / 128, 256, 0, stream>>>(node_bf, Wrest, b_res, resid);
    k_combine_stats<<<(N_NODES + 63) / 64, 256, 0, stream>>>(hacc, resid, h_bias, colsum, colsumsq);
    k_bn<<<512, 256, 0, stream>>>(hacc, colsum, colsumsq, gamma, beta);
}